// Round 21
// baseline (90.465 us; speedup 1.0000x reference)
//
#include <hip/hip_runtime.h>
#include <math.h>

#define NROWS 65536      // B*T
#define DIM   64
#define KCODE 1024
#define TAU_M 2.5e-3f    // margin threshold: eps ~6e-4 (split+accum+4bit-trunc), >4x headroom

typedef __attribute__((ext_vector_type(8))) short short8;
typedef __bf16 bf16_t;
typedef bf16_t bf16x8 __attribute__((ext_vector_type(8)));
typedef __attribute__((ext_vector_type(4))) float f32x4;

union B8 { bf16x8 v; short8 s; ushort u[8]; };

// ws layout (bytes):
//   [0      .. 262143]  ushort emb_frag  (64 tiles x 4KB: ks0hi,ks0lo,ks1hi,ks1lo x lane*16B)
//   [262144 .. 266239]  float  e2h[1024]  = -(||e||^2 - 64) / 2   (shifted: argmin-invariant)
//   [266240 .. 270335]  int    counts[1024]
//   [270336 .. 270339]  float  sse
//   [270340 .. 270343]  uint   nflag
//   [270400 .. 401471]  ushort list[NROWS]  (flagged row ids, compacted)
#define WS_EMBF(ws)   ((ushort*)(ws))
#define WS_E2H(ws)    ((float*)((char*)(ws) + 262144))
#define WS_COUNTS(ws) ((int*)((char*)(ws) + 266240))
#define WS_SSE(ws)    ((float*)((char*)(ws) + 270336))
#define WS_NFLAG(ws)  ((unsigned int*)((char*)(ws) + 270340))
#define WS_LIST(ws)   ((ushort*)((char*)(ws) + 270400))

__device__ __forceinline__ ushort f2bf(float x) {
  unsigned u = __float_as_uint(x);
  u += 0x7FFFu + ((u >> 16) & 1u);           // RNE
  return (ushort)(u >> 16);
}
__device__ __forceinline__ float bf2f(ushort h) {
  return __uint_as_float(((unsigned)h) << 16);
}

// ---------------------------------------------------------------- init ----
// grid 64 blocks x 256 threads; block = one 16-code tile (4KB fragment image).
__global__ __launch_bounds__(256) void vq_init(const float* __restrict__ emb, void* ws) {
  __shared__ __align__(16) ushort timg[2048];   // 4KB tile image
  __shared__ float e2p[256];

  const int g = blockIdx.x, t = threadIdx.x;    // g = global tile (16 codes)
  const int cl = t & 15;                        // local code (= MFMA col)
  const int d0 = (t >> 4) * 4;                  // dim range start
  const int gc = g * 16 + cl;

  const float4 v = *(const float4*)(emb + (size_t)gc * DIM + d0);
  float xs[4] = {v.x, v.y, v.z, v.w};
  float acc = 0.f;
#pragma unroll
  for (int u = 0; u < 4; ++u) {
    int d = d0 + u;
    float x = xs[u];
    ushort hs = f2bf(x);
    ushort ls = f2bf(x - bf2f(hs));
    int ks = d >> 5, kq = (d >> 3) & 3, e = d & 7;
    int lane = cl + kq * 16;
    int off = ks * 1024 + lane * 8 + e;         // ushort units within tile image
    timg[off] = hs;
    timg[off + 512] = ls;
    acc += x * x;
  }
  e2p[t] = acc;
  __syncthreads();
  if (t < 16) {
    float s = 0.f;
#pragma unroll
    for (int j = 0; j < 16; ++j) s += e2p[t + 16 * j];
    WS_E2H(ws)[g * 16 + t] = -0.5f * (s - 64.0f);   // shifted offset
    WS_COUNTS(ws)[g * 16 + t] = 0;
  }
  if (g == 0 && t == 0) { *WS_SSE(ws) = 0.f; *WS_NFLAG(ws) = 0u; }
  __syncthreads();
  ((int4*)WS_EMBF(ws))[g * 256 + t] = ((const int4*)timg)[t];
}

// ---------------------------------------------------------------- main ----
// R15 base (proven best, 77.8us): grid 1024; 512 threads = 8 waves = 2
// row-halves x 4 code-quarters; 64 rows x ALL 1024 codes in-block; wave =
// 32 rows x 256 codes, unroll-in-flight 4 tiles. SINGLE CHANGE vs R15:
// tiles processed in PAIRS with 4 chains = 2 row-groups x 2 tiles, each
// depth-6 with C-init = e2h. Keeps R15's 4-way chain independence (R17
// proved 2-way starves the pipe) while eliminating the p+q v_add per value
// (128 v_add/wave-loop) — the packed top-2 update drops to 3 VALU ops/value.
__global__ __launch_bounds__(512, 1) void vq_main(const float* __restrict__ z,
                                                  const float* __restrict__ emb,
                                                  void* ws,
                                                  float* __restrict__ outp) {
  __shared__ float  e2s[KCODE];  // 4KB
  __shared__ float2 redm[256];   // [wq][64 rows] top-2 m
  __shared__ int    redi[256];   // [wq][64 rows] argmax code
  __shared__ float  z2l[64];
  __shared__ int    win[64];

  const int tid  = threadIdx.x;
  const int lane = tid & 63, w = tid >> 6;
  const int wr = w >> 2, wq = w & 3;
  const int col  = lane & 15, kq = lane >> 4;
  const int rowbase = blockIdx.x * 64 + wr * 32;
  const int tbase = wq * 16;                     // first tile of this wave

  // stage e2h -> LDS (4KB)
  if (tid < 256) ((float4*)e2s)[tid] = ((const float4*)WS_E2H(ws))[tid];

  // A fragments: 2 row-groups-of-16 x 2 ksteps, hi+lo, in registers all kernel.
  B8 ah[2][2], al[2][2];
  float z2p[2];
#pragma unroll
  for (int g = 0; g < 2; ++g) {
    int row = rowbase + g * 16 + col;
    const float* zr = z + (size_t)row * DIM;
    float acc2 = 0.f;
#pragma unroll
    for (int ks = 0; ks < 2; ++ks) {
      const float4* p = (const float4*)(zr + ks * 32 + kq * 8);
      float4 x0 = p[0], x1 = p[1];
      float vv[8] = {x0.x, x0.y, x0.z, x0.w, x1.x, x1.y, x1.z, x1.w};
#pragma unroll
      for (int e = 0; e < 8; ++e) {
        ushort hs = f2bf(vv[e]);
        ah[g][ks].u[e] = hs;
        al[g][ks].u[e] = f2bf(vv[e] - bf2f(hs));
        acc2 = fmaf(vv[e], vv[e], acc2);
      }
    }
    z2p[g] = acc2;
  }
#pragma unroll
  for (int g = 0; g < 2; ++g) {
    z2p[g] += __shfl_xor(z2p[g], 16, 64);
    z2p[g] += __shfl_xor(z2p[g], 32, 64);
  }

  float b1[8], b2[8];   // packed top-2 of m = z.e - (e^2-64)/2; low 4 bits = 15-t
#pragma unroll
  for (int q = 0; q < 8; ++q) { b1[q] = -3.4e38f; b2[q] = -3.4e38f; }

  __syncthreads();      // e2s ready

  // single incremented base + imm offsets for the 8 frag loads per tile-pair
  const char* bb = (const char*)WS_EMBF(ws) + (size_t)tbase * 4096 + lane * 16;
  const int cidx0 = tbase * 16 + col;

#pragma unroll 2
  for (int tp = 0; tp < 8; ++tp) {             // tile pair: tiles 2tp, 2tp+1
    B8 bh0, bl0, bh1, bl1;                     // tile A fragments
    B8 ch0, cl0, ch1, cl1;                     // tile B fragments
    bh0.s = *(const short8*)(bb);
    bl0.s = *(const short8*)(bb + 1024);
    bh1.s = *(const short8*)(bb + 2048);
    bl1.s = *(const short8*)(bb + 3072);
    ch0.s = *(const short8*)(bb + 4096);
    cl0.s = *(const short8*)(bb + 5120);
    ch1.s = *(const short8*)(bb + 6144);
    cl1.s = *(const short8*)(bb + 7168);
    bb += 8192;

    float cA = e2s[cidx0 + (2 * tp) * 16];
    float cB = e2s[cidx0 + (2 * tp + 1) * 16];
    f32x4 ccA = {cA, cA, cA, cA};
    f32x4 ccB = {cB, cB, cB, cB};
    unsigned invTA = 15u - (unsigned)(2 * tp);
    unsigned invTB = 15u - (unsigned)(2 * tp + 1);

    // 4 independent chains (2 row-groups x 2 tiles), depth 6, C-init = e2h
    f32x4 p0 = __builtin_amdgcn_mfma_f32_16x16x32_bf16(ah[0][0].v, bh0.v, ccA, 0, 0, 0);
    f32x4 p1 = __builtin_amdgcn_mfma_f32_16x16x32_bf16(ah[1][0].v, bh0.v, ccA, 0, 0, 0);
    f32x4 q0 = __builtin_amdgcn_mfma_f32_16x16x32_bf16(ah[0][0].v, ch0.v, ccB, 0, 0, 0);
    f32x4 q1 = __builtin_amdgcn_mfma_f32_16x16x32_bf16(ah[1][0].v, ch0.v, ccB, 0, 0, 0);
    p0 = __builtin_amdgcn_mfma_f32_16x16x32_bf16(al[0][0].v, bh0.v, p0, 0, 0, 0);
    p1 = __builtin_amdgcn_mfma_f32_16x16x32_bf16(al[1][0].v, bh0.v, p1, 0, 0, 0);
    q0 = __builtin_amdgcn_mfma_f32_16x16x32_bf16(al[0][0].v, ch0.v, q0, 0, 0, 0);
    q1 = __builtin_amdgcn_mfma_f32_16x16x32_bf16(al[1][0].v, ch0.v, q1, 0, 0, 0);
    p0 = __builtin_amdgcn_mfma_f32_16x16x32_bf16(ah[0][0].v, bl0.v, p0, 0, 0, 0);
    p1 = __builtin_amdgcn_mfma_f32_16x16x32_bf16(ah[1][0].v, bl0.v, p1, 0, 0, 0);
    q0 = __builtin_amdgcn_mfma_f32_16x16x32_bf16(ah[0][0].v, cl0.v, q0, 0, 0, 0);
    q1 = __builtin_amdgcn_mfma_f32_16x16x32_bf16(ah[1][0].v, cl0.v, q1, 0, 0, 0);
    p0 = __builtin_amdgcn_mfma_f32_16x16x32_bf16(ah[0][1].v, bh1.v, p0, 0, 0, 0);
    p1 = __builtin_amdgcn_mfma_f32_16x16x32_bf16(ah[1][1].v, bh1.v, p1, 0, 0, 0);
    q0 = __builtin_amdgcn_mfma_f32_16x16x32_bf16(ah[0][1].v, ch1.v, q0, 0, 0, 0);
    q1 = __builtin_amdgcn_mfma_f32_16x16x32_bf16(ah[1][1].v, ch1.v, q1, 0, 0, 0);
    p0 = __builtin_amdgcn_mfma_f32_16x16x32_bf16(al[0][1].v, bh1.v, p0, 0, 0, 0);
    p1 = __builtin_amdgcn_mfma_f32_16x16x32_bf16(al[1][1].v, bh1.v, p1, 0, 0, 0);
    q0 = __builtin_amdgcn_mfma_f32_16x16x32_bf16(al[0][1].v, ch1.v, q0, 0, 0, 0);
    q1 = __builtin_amdgcn_mfma_f32_16x16x32_bf16(al[1][1].v, ch1.v, q1, 0, 0, 0);
    p0 = __builtin_amdgcn_mfma_f32_16x16x32_bf16(ah[0][1].v, bl1.v, p0, 0, 0, 0);
    p1 = __builtin_amdgcn_mfma_f32_16x16x32_bf16(ah[1][1].v, bl1.v, p1, 0, 0, 0);
    q0 = __builtin_amdgcn_mfma_f32_16x16x32_bf16(ah[0][1].v, cl1.v, q0, 0, 0, 0);
    q1 = __builtin_amdgcn_mfma_f32_16x16x32_bf16(ah[1][1].v, cl1.v, q1, 0, 0, 0);

    // packed top-2 update: 3 VALU ops/value (no p+q add)
#pragma unroll
    for (int g = 0; g < 2; ++g) {
      f32x4 pv = g ? p1 : p0;
      f32x4 qv = g ? q1 : q0;
#pragma unroll
      for (int r = 0; r < 4; ++r) {
        int q = g * 4 + r;
        unsigned mbA = (__float_as_uint(pv[r]) & 0xFFFFFFF0u) | invTA;
        float mpA = __uint_as_float(mbA);
        float nb2A = __builtin_amdgcn_fmed3f(mpA, b1[q], b2[q]);
        b1[q] = fmaxf(b1[q], mpA);
        b2[q] = nb2A;
        unsigned mbB = (__float_as_uint(qv[r]) & 0xFFFFFFF0u) | invTB;
        float mpB = __uint_as_float(mbB);
        float nb2B = __builtin_amdgcn_fmed3f(mpB, b1[q], b2[q]);
        b1[q] = fmaxf(b1[q], mpB);
        b2[q] = nb2B;
      }
    }
  }

  // unpack to explicit (m, code) and top-2 merge across the 16 col-lanes
#pragma unroll
  for (int q = 0; q < 8; ++q) {
    unsigned u1 = __float_as_uint(b1[q]);
    int T1 = 15 - (int)(u1 & 0xFu);
    float m1 = __uint_as_float(u1 & 0xFFFFFFF0u);
    int   c1 = (tbase + T1) * 16 + col;
    float m2 = __uint_as_float(__float_as_uint(b2[q]) & 0xFFFFFFF0u);
#pragma unroll
    for (int off = 1; off <= 8; off <<= 1) {
      float om1 = __shfl_xor(m1, off, 64);
      float om2 = __shfl_xor(m2, off, 64);
      int   oc1 = __shfl_xor(c1, off, 64);
      bool take = (om1 > m1) || (om1 == m1 && oc1 < c1);
      m2 = __builtin_amdgcn_fmed3f(m1, om1, fmaxf(m2, om2));
      m1 = take ? om1 : m1;
      c1 = take ? oc1 : c1;
    }
    if (col == 0) {
      int row = wr * 32 + (q >> 2) * 16 + kq * 4 + (q & 3);   // block-local 0..63
      redm[wq * 64 + row] = make_float2(m1, m2);
      redi[wq * 64 + row] = c1;
    }
  }
  if (wq == 0 && kq == 0) {
#pragma unroll
    for (int g = 0; g < 2; ++g) z2l[wr * 32 + g * 16 + col] = z2p[g];
  }
  __syncthreads();

  // merge the 4 code-quarters; flag / counts / SSE
  if (tid < 64) {
    int row = tid;
    float M1 = -3.4e38f, M2 = -3.4e38f; int C1 = 0x7fffffff;
#pragma unroll
    for (int e = 0; e < 4; ++e) {       // quarters ascend in code: > keeps lowest
      float2 v = redm[e * 64 + row];
      int    ci = redi[e * 64 + row];
      bool take = (v.x > M1) || (v.x == M1 && ci < C1);
      M2 = __builtin_amdgcn_fmed3f(M1, v.x, fmaxf(M2, v.y));
      M1 = take ? v.x : M1;
      C1 = take ? ci : C1;
    }
    int grow = blockIdx.x * 64 + row;
    bool flg = (M1 - M2) < TAU_M;       // uncertified -> fp64 fixup
    win[row] = flg ? -1 : C1;
    if (!flg) {
      atomicAdd(&WS_COUNTS(ws)[C1], 1);
    } else {
      unsigned p = atomicAdd(WS_NFLAG(ws), 1u);
      WS_LIST(ws)[p] = (ushort)grow;
    }
    // ||z-e||^2 = ||z||^2 + 64 - 2*m1
    float ssep = flg ? 0.f : (z2l[row] + 64.0f - 2.0f * M1);
#pragma unroll
    for (int off = 32; off; off >>= 1) ssep += __shfl_down(ssep, off, 64);
    if (tid == 0) atomicAdd(WS_SSE(ws), ssep);
  }
  __syncthreads();

  // quantized_st == emb[winner] in value: write gather directly, no z re-read
  {
    int row = tid >> 3, qtr = tid & 7;
    int wv = win[row];
    if (wv >= 0) {
      size_t grow = (size_t)blockIdx.x * 64 + row;
      const float4* ep = (const float4*)(emb + (size_t)wv * DIM) + qtr * 2;
      float4* op = (float4*)(outp + grow * DIM) + qtr * 2;
      op[0] = ep[0]; op[1] = ep[1];
    }
  }
}

// --------------------------------------------------------------- fixup ----
// fp64 full re-score of flagged rows from the compacted list (load-balanced
// grid-stride); writes their out rows, counts, sse.
__global__ __launch_bounds__(256) void vq_fixup(const float* __restrict__ z,
                                                const float* __restrict__ emb,
                                                void* ws,
                                                float* __restrict__ out) {
  int tid = threadIdx.x;
  __shared__ __align__(16) float zrow[DIM];
  __shared__ double rd[256];
  __shared__ int    ri[256];

  const int n = (int)*WS_NFLAG(ws);

  for (int i = blockIdx.x; i < n; i += 1024) {
    int row = (int)WS_LIST(ws)[i];
    if (tid < 16) *(float4*)&zrow[tid * 4] = ((const float4*)(z + (size_t)row * DIM))[tid];
    __syncthreads();

    double bd = 1e300; int bi = 0x7fffffff;
    for (int c = tid; c < KCODE; c += 256) {
      const float4* e4 = (const float4*)(emb + (size_t)c * DIM);
      double dot = 0.0, e2 = 0.0;
#pragma unroll
      for (int t = 0; t < 16; ++t) {
        float4 v = e4[t];
        float4 zz = *(const float4*)&zrow[t * 4];
        dot = fma((double)zz.x, (double)v.x, dot);
        dot = fma((double)zz.y, (double)v.y, dot);
        dot = fma((double)zz.z, (double)v.z, dot);
        dot = fma((double)zz.w, (double)v.w, dot);
        e2  = fma((double)v.x, (double)v.x, e2);
        e2  = fma((double)v.y, (double)v.y, e2);
        e2  = fma((double)v.z, (double)v.z, e2);
        e2  = fma((double)v.w, (double)v.w, e2);
      }
      double dist = e2 - 2.0 * dot;
      if (dist < bd || (dist == bd && c < bi)) { bd = dist; bi = c; }
    }
    rd[tid] = bd; ri[tid] = bi;
    __syncthreads();
    for (int st = 128; st; st >>= 1) {
      if (tid < st) {
        double od = rd[tid + st]; int oi = ri[tid + st];
        if (od < rd[tid] || (od == rd[tid] && oi < ri[tid])) { rd[tid] = od; ri[tid] = oi; }
      }
      __syncthreads();
    }
    int wi = ri[0];
    if (tid < 16) {
      float4 e  = ((const float4*)(emb + (size_t)wi * DIM))[tid];
      float4 zz = *(const float4*)&zrow[tid * 4];
      float4 qv;
      qv.x = zz.x + (e.x - zz.x); qv.y = zz.y + (e.y - zz.y);
      qv.z = zz.z + (e.z - zz.z); qv.w = zz.w + (e.w - zz.w);
      ((float4*)(out + (size_t)row * DIM))[tid] = qv;
      float dx = zz.x - e.x, dy = zz.y - e.y, dz = zz.z - e.z, dw = zz.w - e.w;
      float part = dx * dx + dy * dy + dz * dz + dw * dw;
      part += __shfl_down(part, 8, 64);
      part += __shfl_down(part, 4, 64);
      part += __shfl_down(part, 2, 64);
      part += __shfl_down(part, 1, 64);
      if (tid == 0) {
        atomicAdd(WS_SSE(ws), part);
        atomicAdd(&WS_COUNTS(ws)[wi], 1);
      }
    }
    __syncthreads();
  }
}

// ------------------------------------------------------------ finalize ----
__global__ __launch_bounds__(256) void vq_finalize(void* ws, float* __restrict__ out) {
  int tid = threadIdx.x;
  __shared__ float w4[4];
  float part = 0.f;
  for (int c = tid; c < KCODE; c += 256) {
    float p = (float)WS_COUNTS(ws)[c] * (1.0f / (float)NROWS);
    part += p * logf(p + 1e-10f);
  }
  for (int off = 32; off; off >>= 1) part += __shfl_down(part, off, 64);
  if ((tid & 63) == 0) w4[tid >> 6] = part;
  __syncthreads();
  if (tid == 0) {
    float ent = (w4[0] + w4[1]) + (w4[2] + w4[3]);
    float perp = expf(-ent);
    perp = fminf(perp, (float)KCODE);
    if (!isfinite(perp)) perp = 0.f;
    out[(size_t)NROWS * DIM]     = 0.25f * (*WS_SSE(ws)) / (float)((size_t)NROWS * DIM);
    out[(size_t)NROWS * DIM + 1] = perp;
  }
}

extern "C" void kernel_launch(void* const* d_in, const int* in_sizes, int n_in,
                              void* d_out, int out_size, void* d_ws, size_t ws_size,
                              hipStream_t stream) {
  const float* z   = (const float*)d_in[0];
  const float* emb = (const float*)d_in[1];
  float* out = (float*)d_out;
  (void)in_sizes; (void)n_in; (void)out_size; (void)ws_size;

  vq_init    <<<64,   256, 0, stream>>>(emb, d_ws);
  vq_main    <<<NROWS / 64, 512, 0, stream>>>(z, emb, d_ws, out);
  vq_fixup   <<<1024, 256, 0, stream>>>(z, emb, d_ws, out);
  vq_finalize<<<1,    256, 0, stream>>>(d_ws, out);
}

// Round 22
// 78.914 us; speedup vs baseline: 1.1464x; 1.1464x over previous
//
#include <hip/hip_runtime.h>
#include <math.h>

#define NROWS 65536      // B*T
#define DIM   64
#define KCODE 1024
#define TAU_M 2.5e-3f    // margin threshold: eps ~6e-4 (split+accum+4bit-trunc), >4x headroom

typedef __attribute__((ext_vector_type(8))) short short8;
typedef __bf16 bf16_t;
typedef bf16_t bf16x8 __attribute__((ext_vector_type(8)));
typedef __attribute__((ext_vector_type(4))) float f32x4;

union B8 { bf16x8 v; short8 s; ushort u[8]; };

// ws layout (bytes):
//   [0      .. 262143]  ushort emb_frag  (64 tiles x 4KB: ks0hi,ks0lo,ks1hi,ks1lo x lane*16B)
//   [262144 .. 266239]  float  e2h[1024]  = -(||e||^2 - 64) / 2   (shifted: argmin-invariant)
//   [266240 .. 270335]  int    counts[1024]
//   [270336 .. 270339]  float  sse
//   [270340 .. 270343]  uint   nflag
//   [270400 .. 401471]  ushort list[NROWS]  (flagged row ids, compacted)
#define WS_EMBF(ws)   ((ushort*)(ws))
#define WS_E2H(ws)    ((float*)((char*)(ws) + 262144))
#define WS_COUNTS(ws) ((int*)((char*)(ws) + 266240))
#define WS_SSE(ws)    ((float*)((char*)(ws) + 270336))
#define WS_NFLAG(ws)  ((unsigned int*)((char*)(ws) + 270340))
#define WS_LIST(ws)   ((ushort*)((char*)(ws) + 270400))

__device__ __forceinline__ ushort f2bf(float x) {
  unsigned u = __float_as_uint(x);
  u += 0x7FFFu + ((u >> 16) & 1u);           // RNE
  return (ushort)(u >> 16);
}
__device__ __forceinline__ float bf2f(ushort h) {
  return __uint_as_float(((unsigned)h) << 16);
}

// ---------------------------------------------------------------- init ----
// grid 64 blocks x 256 threads; block = one 16-code tile (4KB fragment image).
__global__ __launch_bounds__(256) void vq_init(const float* __restrict__ emb, void* ws) {
  __shared__ __align__(16) ushort timg[2048];   // 4KB tile image
  __shared__ float e2p[256];

  const int g = blockIdx.x, t = threadIdx.x;    // g = global tile (16 codes)
  const int cl = t & 15;                        // local code (= MFMA col)
  const int d0 = (t >> 4) * 4;                  // dim range start
  const int gc = g * 16 + cl;

  const float4 v = *(const float4*)(emb + (size_t)gc * DIM + d0);
  float xs[4] = {v.x, v.y, v.z, v.w};
  float acc = 0.f;
#pragma unroll
  for (int u = 0; u < 4; ++u) {
    int d = d0 + u;
    float x = xs[u];
    ushort hs = f2bf(x);
    ushort ls = f2bf(x - bf2f(hs));
    int ks = d >> 5, kq = (d >> 3) & 3, e = d & 7;
    int lane = cl + kq * 16;
    int off = ks * 1024 + lane * 8 + e;         // ushort units within tile image
    timg[off] = hs;
    timg[off + 512] = ls;
    acc += x * x;
  }
  e2p[t] = acc;
  __syncthreads();
  if (t < 16) {
    float s = 0.f;
#pragma unroll
    for (int j = 0; j < 16; ++j) s += e2p[t + 16 * j];
    WS_E2H(ws)[g * 16 + t] = -0.5f * (s - 64.0f);   // shifted offset
    WS_COUNTS(ws)[g * 16 + t] = 0;
  }
  if (g == 0 && t == 0) { *WS_SSE(ws) = 0.f; *WS_NFLAG(ws) = 0u; }
  __syncthreads();
  ((int4*)WS_EMBF(ws))[g * 256 + t] = ((const int4*)timg)[t];
}

// ---------------------------------------------------------------- main ----
// FINAL configuration (best measured: 77.8us total, re-confirmed 78.8):
// grid 1024; block = 512 threads = 8 waves = 2 row-halves x 4 code-quarters;
// block covers 64 rows x ALL 1024 codes -> merge/flag/SSE/gather all
// in-block (standalone merge kernels measured 3-4x slower, twice: R11/R16).
// Wave = 32 rows x 256 codes (16 tiles), unroll 4, 4 independent DEPTH-3
// MFMA chains per tile (depth-6 variants regressed 27% twice — R17/R21:
// chain depth is the poison at ~2.6 waves/SIMD; p+q adds are cheaper than
// the serialization they avoid).
__global__ __launch_bounds__(512, 1) void vq_main(const float* __restrict__ z,
                                                  const float* __restrict__ emb,
                                                  void* ws,
                                                  float* __restrict__ outp) {
  __shared__ float  e2s[KCODE];  // 4KB
  __shared__ float2 redm[256];   // [wq][64 rows] top-2 m
  __shared__ int    redi[256];   // [wq][64 rows] argmax code
  __shared__ float  z2l[64];
  __shared__ int    win[64];

  const int tid  = threadIdx.x;
  const int lane = tid & 63, w = tid >> 6;
  const int wr = w >> 2, wq = w & 3;
  const int col  = lane & 15, kq = lane >> 4;
  const int rowbase = blockIdx.x * 64 + wr * 32;
  const int tbase = wq * 16;                     // first tile of this wave

  // stage e2h -> LDS (4KB)
  if (tid < 256) ((float4*)e2s)[tid] = ((const float4*)WS_E2H(ws))[tid];

  // A fragments: 2 row-groups-of-16 x 2 ksteps, hi+lo, in registers all kernel.
  B8 ah[2][2], al[2][2];
  float z2p[2];
#pragma unroll
  for (int g = 0; g < 2; ++g) {
    int row = rowbase + g * 16 + col;
    const float* zr = z + (size_t)row * DIM;
    float acc2 = 0.f;
#pragma unroll
    for (int ks = 0; ks < 2; ++ks) {
      const float4* p = (const float4*)(zr + ks * 32 + kq * 8);
      float4 x0 = p[0], x1 = p[1];
      float vv[8] = {x0.x, x0.y, x0.z, x0.w, x1.x, x1.y, x1.z, x1.w};
#pragma unroll
      for (int e = 0; e < 8; ++e) {
        ushort hs = f2bf(vv[e]);
        ah[g][ks].u[e] = hs;
        al[g][ks].u[e] = f2bf(vv[e] - bf2f(hs));
        acc2 = fmaf(vv[e], vv[e], acc2);
      }
    }
    z2p[g] = acc2;
  }
#pragma unroll
  for (int g = 0; g < 2; ++g) {
    z2p[g] += __shfl_xor(z2p[g], 16, 64);
    z2p[g] += __shfl_xor(z2p[g], 32, 64);
  }

  float b1[8], b2[8];   // packed top-2 of m = z.e - (e^2-64)/2; low 4 bits = 15-t
#pragma unroll
  for (int q = 0; q < 8; ++q) { b1[q] = -3.4e38f; b2[q] = -3.4e38f; }

  __syncthreads();      // e2s ready

  // single incremented base + imm offsets (1024/2048/3072) for the 4 frag loads
  const char* bb = (const char*)WS_EMBF(ws) + (size_t)tbase * 4096 + lane * 16;
  const int cidx0 = tbase * 16 + col;

#pragma unroll 4
  for (int t = 0; t < 16; ++t) {
    B8 bh0, bl0, bh1, bl1;
    bh0.s = *(const short8*)(bb);
    bl0.s = *(const short8*)(bb + 1024);
    bh1.s = *(const short8*)(bb + 2048);
    bl1.s = *(const short8*)(bb + 3072);
    bb += 4096;

    float cinit = e2s[cidx0 + t * 16];
    f32x4 cc = {cinit, cinit, cinit, cinit};
    f32x4 zz4 = {0.f, 0.f, 0.f, 0.f};
    unsigned invT = 15u - (unsigned)t;

    // 4 independent chains, depth 3 each
    f32x4 p0 = __builtin_amdgcn_mfma_f32_16x16x32_bf16(ah[0][0].v, bh0.v, cc, 0, 0, 0);
    f32x4 p1 = __builtin_amdgcn_mfma_f32_16x16x32_bf16(ah[1][0].v, bh0.v, cc, 0, 0, 0);
    f32x4 q0 = __builtin_amdgcn_mfma_f32_16x16x32_bf16(ah[0][0].v, bl0.v, zz4, 0, 0, 0);
    f32x4 q1 = __builtin_amdgcn_mfma_f32_16x16x32_bf16(ah[1][0].v, bl0.v, zz4, 0, 0, 0);
    p0 = __builtin_amdgcn_mfma_f32_16x16x32_bf16(al[0][0].v, bh0.v, p0, 0, 0, 0);
    p1 = __builtin_amdgcn_mfma_f32_16x16x32_bf16(al[1][0].v, bh0.v, p1, 0, 0, 0);
    q0 = __builtin_amdgcn_mfma_f32_16x16x32_bf16(al[0][1].v, bh1.v, q0, 0, 0, 0);
    q1 = __builtin_amdgcn_mfma_f32_16x16x32_bf16(al[1][1].v, bh1.v, q1, 0, 0, 0);
    p0 = __builtin_amdgcn_mfma_f32_16x16x32_bf16(ah[0][1].v, bh1.v, p0, 0, 0, 0);
    p1 = __builtin_amdgcn_mfma_f32_16x16x32_bf16(ah[1][1].v, bh1.v, p1, 0, 0, 0);
    q0 = __builtin_amdgcn_mfma_f32_16x16x32_bf16(ah[0][1].v, bl1.v, q0, 0, 0, 0);
    q1 = __builtin_amdgcn_mfma_f32_16x16x32_bf16(ah[1][1].v, bl1.v, q1, 0, 0, 0);

#pragma unroll
    for (int g = 0; g < 2; ++g) {
      f32x4 pv = g ? p1 : p0;
      f32x4 qv = g ? q1 : q0;
#pragma unroll
      for (int r = 0; r < 4; ++r) {
        int q = g * 4 + r;
        float m = pv[r] + qv[r];
        unsigned mb = (__float_as_uint(m) & 0xFFFFFFF0u) | invT;
        float mp = __uint_as_float(mb);
        float nb2 = __builtin_amdgcn_fmed3f(mp, b1[q], b2[q]);
        b1[q] = fmaxf(b1[q], mp);
        b2[q] = nb2;
      }
    }
  }

  // unpack to explicit (m, code) and top-2 merge across the 16 col-lanes
#pragma unroll
  for (int q = 0; q < 8; ++q) {
    unsigned u1 = __float_as_uint(b1[q]);
    int T1 = 15 - (int)(u1 & 0xFu);
    float m1 = __uint_as_float(u1 & 0xFFFFFFF0u);
    int   c1 = (tbase + T1) * 16 + col;
    float m2 = __uint_as_float(__float_as_uint(b2[q]) & 0xFFFFFFF0u);
#pragma unroll
    for (int off = 1; off <= 8; off <<= 1) {
      float om1 = __shfl_xor(m1, off, 64);
      float om2 = __shfl_xor(m2, off, 64);
      int   oc1 = __shfl_xor(c1, off, 64);
      bool take = (om1 > m1) || (om1 == m1 && oc1 < c1);
      m2 = __builtin_amdgcn_fmed3f(m1, om1, fmaxf(m2, om2));
      m1 = take ? om1 : m1;
      c1 = take ? oc1 : c1;
    }
    if (col == 0) {
      int row = wr * 32 + (q >> 2) * 16 + kq * 4 + (q & 3);   // block-local 0..63
      redm[wq * 64 + row] = make_float2(m1, m2);
      redi[wq * 64 + row] = c1;
    }
  }
  if (wq == 0 && kq == 0) {
#pragma unroll
    for (int g = 0; g < 2; ++g) z2l[wr * 32 + g * 16 + col] = z2p[g];
  }
  __syncthreads();

  // merge the 4 code-quarters; flag / counts / SSE
  if (tid < 64) {
    int row = tid;
    float M1 = -3.4e38f, M2 = -3.4e38f; int C1 = 0x7fffffff;
#pragma unroll
    for (int e = 0; e < 4; ++e) {       // quarters ascend in code: > keeps lowest
      float2 v = redm[e * 64 + row];
      int    ci = redi[e * 64 + row];
      bool take = (v.x > M1) || (v.x == M1 && ci < C1);
      M2 = __builtin_amdgcn_fmed3f(M1, v.x, fmaxf(M2, v.y));
      M1 = take ? v.x : M1;
      C1 = take ? ci : C1;
    }
    int grow = blockIdx.x * 64 + row;
    bool flg = (M1 - M2) < TAU_M;       // uncertified -> fp64 fixup
    win[row] = flg ? -1 : C1;
    if (!flg) {
      atomicAdd(&WS_COUNTS(ws)[C1], 1);
    } else {
      unsigned p = atomicAdd(WS_NFLAG(ws), 1u);
      WS_LIST(ws)[p] = (ushort)grow;
    }
    // ||z-e||^2 = ||z||^2 + 64 - 2*m1
    float ssep = flg ? 0.f : (z2l[row] + 64.0f - 2.0f * M1);
#pragma unroll
    for (int off = 32; off; off >>= 1) ssep += __shfl_down(ssep, off, 64);
    if (tid == 0) atomicAdd(WS_SSE(ws), ssep);
  }
  __syncthreads();

  // quantized_st == emb[winner] in value: write gather directly, no z re-read
  {
    int row = tid >> 3, qtr = tid & 7;
    int wv = win[row];
    if (wv >= 0) {
      size_t grow = (size_t)blockIdx.x * 64 + row;
      const float4* ep = (const float4*)(emb + (size_t)wv * DIM) + qtr * 2;
      float4* op = (float4*)(outp + grow * DIM) + qtr * 2;
      op[0] = ep[0]; op[1] = ep[1];
    }
  }
}

// --------------------------------------------------------------- fixup ----
// fp64 full re-score of flagged rows from the compacted list (load-balanced
// grid-stride); writes their out rows, counts, sse.
__global__ __launch_bounds__(256) void vq_fixup(const float* __restrict__ z,
                                                const float* __restrict__ emb,
                                                void* ws,
                                                float* __restrict__ out) {
  int tid = threadIdx.x;
  __shared__ __align__(16) float zrow[DIM];
  __shared__ double rd[256];
  __shared__ int    ri[256];

  const int n = (int)*WS_NFLAG(ws);

  for (int i = blockIdx.x; i < n; i += 1024) {
    int row = (int)WS_LIST(ws)[i];
    if (tid < 16) *(float4*)&zrow[tid * 4] = ((const float4*)(z + (size_t)row * DIM))[tid];
    __syncthreads();

    double bd = 1e300; int bi = 0x7fffffff;
    for (int c = tid; c < KCODE; c += 256) {
      const float4* e4 = (const float4*)(emb + (size_t)c * DIM);
      double dot = 0.0, e2 = 0.0;
#pragma unroll
      for (int t = 0; t < 16; ++t) {
        float4 v = e4[t];
        float4 zz = *(const float4*)&zrow[t * 4];
        dot = fma((double)zz.x, (double)v.x, dot);
        dot = fma((double)zz.y, (double)v.y, dot);
        dot = fma((double)zz.z, (double)v.z, dot);
        dot = fma((double)zz.w, (double)v.w, dot);
        e2  = fma((double)v.x, (double)v.x, e2);
        e2  = fma((double)v.y, (double)v.y, e2);
        e2  = fma((double)v.z, (double)v.z, e2);
        e2  = fma((double)v.w, (double)v.w, e2);
      }
      double dist = e2 - 2.0 * dot;
      if (dist < bd || (dist == bd && c < bi)) { bd = dist; bi = c; }
    }
    rd[tid] = bd; ri[tid] = bi;
    __syncthreads();
    for (int st = 128; st; st >>= 1) {
      if (tid < st) {
        double od = rd[tid + st]; int oi = ri[tid + st];
        if (od < rd[tid] || (od == rd[tid] && oi < ri[tid])) { rd[tid] = od; ri[tid] = oi; }
      }
      __syncthreads();
    }
    int wi = ri[0];
    if (tid < 16) {
      float4 e  = ((const float4*)(emb + (size_t)wi * DIM))[tid];
      float4 zz = *(const float4*)&zrow[tid * 4];
      float4 qv;
      qv.x = zz.x + (e.x - zz.x); qv.y = zz.y + (e.y - zz.y);
      qv.z = zz.z + (e.z - zz.z); qv.w = zz.w + (e.w - zz.w);
      ((float4*)(out + (size_t)row * DIM))[tid] = qv;
      float dx = zz.x - e.x, dy = zz.y - e.y, dz = zz.z - e.z, dw = zz.w - e.w;
      float part = dx * dx + dy * dy + dz * dz + dw * dw;
      part += __shfl_down(part, 8, 64);
      part += __shfl_down(part, 4, 64);
      part += __shfl_down(part, 2, 64);
      part += __shfl_down(part, 1, 64);
      if (tid == 0) {
        atomicAdd(WS_SSE(ws), part);
        atomicAdd(&WS_COUNTS(ws)[wi], 1);
      }
    }
    __syncthreads();
  }
}

// ------------------------------------------------------------ finalize ----
__global__ __launch_bounds__(256) void vq_finalize(void* ws, float* __restrict__ out) {
  int tid = threadIdx.x;
  __shared__ float w4[4];
  float part = 0.f;
  for (int c = tid; c < KCODE; c += 256) {
    float p = (float)WS_COUNTS(ws)[c] * (1.0f / (float)NROWS);
    part += p * logf(p + 1e-10f);
  }
  for (int off = 32; off; off >>= 1) part += __shfl_down(part, off, 64);
  if ((tid & 63) == 0) w4[tid >> 6] = part;
  __syncthreads();
  if (tid == 0) {
    float ent = (w4[0] + w4[1]) + (w4[2] + w4[3]);
    float perp = expf(-ent);
    perp = fminf(perp, (float)KCODE);
    if (!isfinite(perp)) perp = 0.f;
    out[(size_t)NROWS * DIM]     = 0.25f * (*WS_SSE(ws)) / (float)((size_t)NROWS * DIM);
    out[(size_t)NROWS * DIM + 1] = perp;
  }
}

extern "C" void kernel_launch(void* const* d_in, const int* in_sizes, int n_in,
                              void* d_out, int out_size, void* d_ws, size_t ws_size,
                              hipStream_t stream) {
  const float* z   = (const float*)d_in[0];
  const float* emb = (const float*)d_in[1];
  float* out = (float*)d_out;
  (void)in_sizes; (void)n_in; (void)out_size; (void)ws_size;

  vq_init    <<<64,   256, 0, stream>>>(emb, d_ws);
  vq_main    <<<NROWS / 64, 512, 0, stream>>>(z, emb, d_ws, out);
  vq_fixup   <<<1024, 256, 0, stream>>>(z, emb, d_ws, out);
  vq_finalize<<<1,    256, 0, stream>>>(d_ws, out);
}